// Round 15
// baseline (93.942 us; speedup 1.0000x reference)
//
#include <hip/hip_runtime.h>

// ---------------------------------------------------------------------------
// TreeEncoder, round 15: persistent weights via TWO 256-thread kernels.
//   r12-r14: 1024-thread blocks are hard-clamped to 64 VGPR by the toolchain
//   (three knobs tried) -> persistent-weight P/C impossible in one block.
//   256-thread blocks are proven honest up to ~148 VGPR (r7).  So split:
//   - enc_l0: block = 4 waves x (256 rows, one col-half).  Wave w persists
//     W0 slice t=H*4+w (48 VGPR) + 2 emb frags.  h0 via small LDS buffer
//     (2 barriers/tile); h1 -> global bf16 buffer in d_ws (32MB, L3).
//   - enc_l1: persistent W1 slice; A-frags read DIRECTLY from row-major h1
//     (per-lane 16B contiguous) -> no LDS, no barriers; WAR prefetch of the
//     next tile's A during activations; one atomicAdd per col.
//   Weight traffic 852MB -> ~82MB (one load per wave per kernel).
//   Prep kernel: 53 x 256 (was 209 x 64; ~7us of launch/evaluation cost).
//   Numerics identical to r11 (Pade[3/2] merged activation, bf16 h).
// ---------------------------------------------------------------------------

typedef short bf16x8 __attribute__((ext_vector_type(8)));
typedef float f32x4  __attribute__((ext_vector_type(4)));

#define MFMA16(a, b, c) __builtin_amdgcn_mfma_f32_16x16x32_bf16((a), (b), (c), 0, 0, 0)

#define NEG_L2E (-1.44269504088896f)
#define TWO_L2E (2.88539008177793f)

#define H1_OFS (4u << 20)          // h1 buffer at ws + 4MB (bf16 [131072][128])

__device__ __forceinline__ unsigned short f2bf(float f) {
    return (unsigned short)((__float_as_uint(f) + 0x8000u) >> 16);
}
__device__ __forceinline__ float frcp(float x)  { return __builtin_amdgcn_rcpf(x); }
__device__ __forceinline__ float fexp2(float x) { return __builtin_amdgcn_exp2f(x); }

// Pade[3/2] merged activation (r11 numerics): pre-scaled logits
__device__ __forceinline__ float act_h(float iv, float ov, float cv) {
    float ei = fexp2(iv);
    float eo = fexp2(ov);
    float u  = fexp2(cv);
    float p  = u - 1.0f;
    float q  = (1.0f + ei) * (u + 1.0f);     // cc = p/q = sig(i)*tanh(c~)
    float p2 = p * p, q2 = q * q;
    float t15 = 15.0f * q2;
    return (p * (t15 + p2)) * frcp((q * (6.0f * p2 + t15)) * (1.0f + eo));
}

__device__ __forceinline__ bf16x8 pack8(float4 v0, float4 v1) {
    bf16x8 a;
    a[0] = (short)f2bf(v0.x); a[1] = (short)f2bf(v0.y);
    a[2] = (short)f2bf(v0.z); a[3] = (short)f2bf(v0.w);
    a[4] = (short)f2bf(v1.x); a[5] = (short)f2bf(v1.y);
    a[6] = (short)f2bf(v1.z); a[7] = (short)f2bf(v1.w);
    return a;
}

// ---------------------------------------------------------------------------
// Prep (53 blocks x 256): same ws layout as rounds 8-14.
//   [0,16384) emb frags; [16384,212992) gate frags; [212992,216064) biases.
// ---------------------------------------------------------------------------
__global__ void prep_frags(const float* __restrict__ embW,
                           const float* __restrict__ Wi,
                           const float* __restrict__ Wo,
                           const float* __restrict__ Wc,
                           const float* __restrict__ bWi, const float* __restrict__ bUi,
                           const float* __restrict__ bWo, const float* __restrict__ bUo,
                           const float* __restrict__ bWc, const float* __restrict__ bUc,
                           char* __restrict__ ws) {
    const int tid = threadIdx.x;
    const int fb  = blockIdx.x * 4 + (tid >> 6);
    const int l   = tid & 63;

    if (fb < 208) {
        int g  = l >> 4, c0 = l & 15;
        const float* src;
        int t, kk;
        size_t dst;
        float scale;
        if (fb < 16) {
            t = fb >> 1; kk = fb & 1;
            src = embW;                                   // [64][128]
            dst = (size_t)fb * 1024;
            scale = 1.0f;
        } else {
            int r = fb - 16;                              // (layer*8+t)*12+gate*4+kk
            int layer = r / 96;
            int r2 = r % 96;
            t = r2 / 12;
            int r3 = r2 % 12;
            int gate = r3 >> 2;
            kk = r3 & 3;
            const float* Ws[3] = {Wi, Wo, Wc};
            src = Ws[gate] + (size_t)layer * 128 * 128;   // [128][128]
            dst = 16384 + (size_t)r * 1024;
            scale = (gate == 2) ? TWO_L2E : NEG_L2E;
        }
        bf16x8 v;
#pragma unroll
        for (int e = 0; e < 8; ++e) {
            int k   = kk * 32 + g * 8 + e;
            int col = t * 16 + c0;
            v[e] = (short)f2bf(scale * src[(size_t)k * 128 + col]);
        }
        *reinterpret_cast<bf16x8*>(ws + dst + (size_t)l * 16) = v;
    } else if (blockIdx.x == 52) {
        // combined scaled biases: float[2][3][128]
        float* bias = reinterpret_cast<float*>(ws + 212992);
#pragma unroll
        for (int j = 0; j < 3; ++j) {
            int v = j * 256 + tid;              // 0..767
            int layer = v / 384;
            int r = v % 384;
            int gate = r >> 7;
            int c = r & 127;
            int idx = layer * 128 + c;
            float x;
            if (gate == 0)      x = NEG_L2E * (bWi[idx] + bUi[idx]);
            else if (gate == 1) x = NEG_L2E * (bWo[idx] + bUo[idx]);
            else                x = TWO_L2E * (bWc[idx] + bUc[idx]);
            bias[v] = x;
        }
    }
}

// ---------------------------------------------------------------------------
// Kernel A: embedding + layer 0.  1024 blocks x 256 threads.
//   bid: H = bid&1 (col half), rowbase = (bid>>1)*256.  Wave w: t_out = H*4+w.
//   Per 32-row tile: embed (wave w does emb cols t=w and t=w+4) -> LDS ->
//   barrier -> A-frags -> barrier -> 24 MFMA with persistent W0 -> act ->
//   h1 (bf16, global).  X for tile+1 loaded WAR-style after A-read.
// ---------------------------------------------------------------------------
__global__ __launch_bounds__(256) void enc_l0(
        const float* __restrict__ X,       // [131072][64]
        const float* __restrict__ emb_b,   // [128]
        const char*  __restrict__ frags,   // ws
        unsigned short* __restrict__ h1) { // bf16 [131072][128]

    __shared__ __align__(16) unsigned short hbuf[32][136];   // 8704 B

    const int tid = threadIdx.x;
    const int w   = tid >> 6;
    const int l   = tid & 63;
    const int g   = l >> 4;
    const int c0  = l & 15;
    const int H   = blockIdx.x & 1;
    const int rowbase = (blockIdx.x >> 1) * 256;
    const int t_out   = H * 4 + w;
    const int ct      = t_out * 16 + c0;

    const float* biasf = reinterpret_cast<const float*>(frags + 212992);
    const float Bi = biasf[ct];
    const float Bo = biasf[128 + ct];
    const float Bc = biasf[256 + ct];

    // persistent W0 t-slice: 12 frags (48 VGPR)
    bf16x8 W0[12];
    {
        const char* fb = frags + 16384 + (size_t)(t_out * 12) * 1024 + (size_t)l * 16;
#pragma unroll
        for (int i = 0; i < 12; ++i)
            W0[i] = *reinterpret_cast<const bf16x8*>(fb + (size_t)i * 1024);
    }
    // persistent emb frags for t_e = w and w+4 (16 VGPR) + emb biases
    bf16x8 EMB[2][2];
    float  be[2];
#pragma unroll
    for (int te = 0; te < 2; ++te) {
        int tt = w + te * 4;
        const char* eb = frags + (size_t)(tt * 2) * 1024 + (size_t)l * 16;
        EMB[te][0] = *reinterpret_cast<const bf16x8*>(eb);
        EMB[te][1] = *reinterpret_cast<const bf16x8*>(eb + 1024);
        be[te]     = emb_b[tt * 16 + c0];
    }

    // prologue: X A-frags for tile 0
    bf16x8 afr[2][2];
#pragma unroll
    for (int mi = 0; mi < 2; ++mi) {
        const float* xr = X + (size_t)(rowbase + mi * 16 + c0) * 64;
        float4 v0 = *reinterpret_cast<const float4*>(xr + g * 8);
        float4 v1 = *reinterpret_cast<const float4*>(xr + g * 8 + 4);
        float4 v2 = *reinterpret_cast<const float4*>(xr + 32 + g * 8);
        float4 v3 = *reinterpret_cast<const float4*>(xr + 32 + g * 8 + 4);
        afr[mi][0] = pack8(v0, v1);
        afr[mi][1] = pack8(v2, v3);
    }

    for (int tile = 0; tile < 8; ++tile) {
        const int rb = rowbase + tile * 32;

        // -------- embed this tile's h0 (wave w: cols of t=w and t=w+4) ----
#pragma unroll
        for (int te = 0; te < 2; ++te) {
            const int tc = (w + te * 4) * 16 + c0;
#pragma unroll
            for (int mi = 0; mi < 2; ++mi) {
                f32x4 acc = {be[te], be[te], be[te], be[te]};
                acc = MFMA16(afr[mi][0], EMB[te][0], acc);
                acc = MFMA16(afr[mi][1], EMB[te][1], acc);
#pragma unroll
                for (int r = 0; r < 4; ++r)
                    hbuf[mi * 16 + g * 4 + r][tc] = f2bf(acc[r]);
            }
        }
        __syncthreads();

        // -------- A-frags of h0 --------
        bf16x8 A[2][4];
#pragma unroll
        for (int mi = 0; mi < 2; ++mi)
#pragma unroll
            for (int kk = 0; kk < 4; ++kk)
                A[mi][kk] = *reinterpret_cast<const bf16x8*>(
                        &hbuf[mi * 16 + c0][kk * 32 + g * 8]);
        __syncthreads();

        // -------- X prefetch for tile+1 (WAR on afr; hides under MFMA/act)
        if (tile < 7) {
#pragma unroll
            for (int mi = 0; mi < 2; ++mi) {
                const float* xr = X + (size_t)(rb + 32 + mi * 16 + c0) * 64;
                float4 v0 = *reinterpret_cast<const float4*>(xr + g * 8);
                float4 v1 = *reinterpret_cast<const float4*>(xr + g * 8 + 4);
                float4 v2 = *reinterpret_cast<const float4*>(xr + 32 + g * 8);
                float4 v3 = *reinterpret_cast<const float4*>(xr + 32 + g * 8 + 4);
                afr[mi][0] = pack8(v0, v1);
                afr[mi][1] = pack8(v2, v3);
            }
        }

        // -------- layer 0: 24 MFMA with persistent W0, bias-splat init ----
        f32x4 ai[2] = { f32x4{Bi, Bi, Bi, Bi}, f32x4{Bi, Bi, Bi, Bi} };
        f32x4 ao[2] = { f32x4{Bo, Bo, Bo, Bo}, f32x4{Bo, Bo, Bo, Bo} };
        f32x4 ac[2] = { f32x4{Bc, Bc, Bc, Bc}, f32x4{Bc, Bc, Bc, Bc} };
#pragma unroll
        for (int kk = 0; kk < 4; ++kk) {
#pragma unroll
            for (int mi = 0; mi < 2; ++mi) {
                ac[mi] = MFMA16(A[mi][kk], W0[8 + kk], ac[mi]);
                ai[mi] = MFMA16(A[mi][kk], W0[kk],     ai[mi]);
                ao[mi] = MFMA16(A[mi][kk], W0[4 + kk], ao[mi]);
            }
        }

        // -------- activation + h1 store (bf16, row-major) --------
#pragma unroll
        for (int mi = 0; mi < 2; ++mi) {
#pragma unroll
            for (int r = 0; r < 4; ++r) {
                float h = act_h(ai[mi][r], ao[mi][r], ac[mi][r]);
                h1[(size_t)(rb + mi * 16 + g * 4 + r) * 128 + ct] = f2bf(h);
            }
        }
    }
}

// ---------------------------------------------------------------------------
// Kernel B: layer 1 + mean.  1024 blocks x 256 threads, ZERO barriers.
//   A-frags read directly from row-major h1 (16B/lane contiguous).
//   WAR single-buffer: next tile's A loads issue after this tile's MFMAs.
// ---------------------------------------------------------------------------
__global__ __launch_bounds__(256) void enc_l1(
        const unsigned short* __restrict__ h1,   // bf16 [131072][128]
        const char*  __restrict__ frags,
        float* __restrict__ out) {               // [256][128]

    const int tid = threadIdx.x;
    const int w   = tid >> 6;
    const int l   = tid & 63;
    const int g   = l >> 4;
    const int c0  = l & 15;
    const int H   = blockIdx.x & 1;
    const int rowbase = (blockIdx.x >> 1) * 256;
    const int batch   = rowbase >> 9;
    const int t_out   = H * 4 + w;
    const int ct      = t_out * 16 + c0;

    const float* biasf = reinterpret_cast<const float*>(frags + 212992);
    const float Bi = biasf[384 + ct];
    const float Bo = biasf[384 + 128 + ct];
    const float Bc = biasf[384 + 256 + ct];

    // persistent W1 t-slice: 12 frags (48 VGPR)
    bf16x8 W1[12];
    {
        const char* fb = frags + 16384 + (size_t)((8 + t_out) * 12) * 1024 + (size_t)l * 16;
#pragma unroll
        for (int i = 0; i < 12; ++i)
            W1[i] = *reinterpret_cast<const bf16x8*>(fb + (size_t)i * 1024);
    }

    // prologue: A-frags of tile 0 straight from h1
    bf16x8 A[2][4];
#pragma unroll
    for (int mi = 0; mi < 2; ++mi)
#pragma unroll
        for (int kk = 0; kk < 4; ++kk)
            A[mi][kk] = *reinterpret_cast<const bf16x8*>(
                    &h1[(size_t)(rowbase + mi * 16 + c0) * 128 + kk * 32 + g * 8]);

    float msum = 0.0f;

    for (int tile = 0; tile < 8; ++tile) {
        f32x4 ai[2] = { f32x4{Bi, Bi, Bi, Bi}, f32x4{Bi, Bi, Bi, Bi} };
        f32x4 ao[2] = { f32x4{Bo, Bo, Bo, Bo}, f32x4{Bo, Bo, Bo, Bo} };
        f32x4 ac[2] = { f32x4{Bc, Bc, Bc, Bc}, f32x4{Bc, Bc, Bc, Bc} };
#pragma unroll
        for (int kk = 0; kk < 4; ++kk) {
#pragma unroll
            for (int mi = 0; mi < 2; ++mi) {
                ac[mi] = MFMA16(A[mi][kk], W1[8 + kk], ac[mi]);
                ai[mi] = MFMA16(A[mi][kk], W1[kk],     ai[mi]);
                ao[mi] = MFMA16(A[mi][kk], W1[4 + kk], ao[mi]);
            }
        }

        // WAR reload: next tile's A; latency hides under activations
        if (tile < 7) {
            const size_t rb2 = (size_t)(rowbase + (tile + 1) * 32);
#pragma unroll
            for (int mi = 0; mi < 2; ++mi)
#pragma unroll
                for (int kk = 0; kk < 4; ++kk)
                    A[mi][kk] = *reinterpret_cast<const bf16x8*>(
                            &h1[(rb2 + mi * 16 + c0) * 128 + kk * 32 + g * 8]);
        }

#pragma unroll
        for (int mi = 0; mi < 2; ++mi)
#pragma unroll
            for (int r = 0; r < 4; ++r)
                msum += act_h(ai[mi][r], ao[mi][r], ac[mi][r]);
    }

    // mean partials: col ct is unique to this wave; reduce across g-groups
    msum += __shfl_xor(msum, 16);
    msum += __shfl_xor(msum, 32);
    if (g == 0)
        atomicAdd(&out[batch * 128 + ct], msum * (1.0f / 512.0f));
}

// ---------------------------------------------------------------------------
extern "C" void kernel_launch(void* const* d_in, const int* in_sizes, int n_in,
                              void* d_out, int out_size, void* d_ws, size_t ws_size,
                              hipStream_t stream) {
    const float* X    = (const float*)d_in[0];
    const float* embW = (const float*)d_in[1];
    const float* embb = (const float*)d_in[2];
    const float* Wi   = (const float*)d_in[3];
    const float* Wo   = (const float*)d_in[4];
    const float* Wc   = (const float*)d_in[5];
    const float* bWi  = (const float*)d_in[6];
    const float* bUi  = (const float*)d_in[7];
    const float* bWo  = (const float*)d_in[8];
    const float* bUo  = (const float*)d_in[9];
    const float* bWc  = (const float*)d_in[10];
    const float* bUc  = (const float*)d_in[11];
    float* out = (float*)d_out;
    char*  ws  = (char*)d_ws;
    unsigned short* h1 = (unsigned short*)(ws + H1_OFS);

    hipMemsetAsync(d_out, 0, (size_t)out_size * sizeof(float), stream);
    prep_frags<<<53, 256, 0, stream>>>(embW, Wi, Wo, Wc,
                                       bWi, bUi, bWo, bUo, bWc, bUc, ws);
    enc_l0<<<1024, 256, 0, stream>>>(X, embb, (const char*)ws, h1);
    enc_l1<<<1024, 256, 0, stream>>>(h1, (const char*)ws, out);
}

// Round 16
// 58.822 us; speedup vs baseline: 1.5971x; 1.5971x over previous
//
#include <hip/hip_runtime.h>

// ---------------------------------------------------------------------------
// TreeEncoder, round 16: designed for the 64-VGPR / 8-waves-per-EU rung.
//   m69: VGPR granule is 64 -> occupancy rungs are {64:8, 128:4, 256:2}
//   waves/EU.  r8-r15 all needed ~116-150 regs -> stuck on the 4-wave rung
//   at a ~58us kernel wall regardless of schedule; the only measured lever
//   was wave count (3w=83, 4w=59, 2w=76).  This round fits the 8-wave rung:
//   - 16 rows/wave (A-frags 16 regs), 2048 blocks x 256 threads, 8 blocks/CU.
//   - weights LDS-staged via global_load_lds (ZERO staging VGPRs, async;
//     issued between the two per-step barriers, latency hidden by reg-only
//     activations), read per-gate (transient 4-12 regs, no 48-reg buffer).
//   - A0 (h0) + A1 (h1, accumulated at odd steps) = 32 regs; accs 12;
//     wave-private slab transpose (r9-verified); per-step shuffle-reduce to
//     LDS kills msum[8].  Audit ~62 live peak.
//   - LDS: sbuf 12.3K + slabs 5K + redbuf 2K = 19.4 KB -> 8 blocks/CU.
// ---------------------------------------------------------------------------

typedef short bf16x8 __attribute__((ext_vector_type(8)));
typedef float f32x4  __attribute__((ext_vector_type(4)));

#define MFMA16(a, b, c) __builtin_amdgcn_mfma_f32_16x16x32_bf16((a), (b), (c), 0, 0, 0)

#define NEG_L2E (-1.44269504088896f)
#define TWO_L2E (2.88539008177793f)

__device__ __forceinline__ unsigned short f2bf(float f) {
    return (unsigned short)((__float_as_uint(f) + 0x8000u) >> 16);
}
__device__ __forceinline__ float frcp(float x)  { return __builtin_amdgcn_rcpf(x); }
__device__ __forceinline__ float fexp2(float x) { return __builtin_amdgcn_exp2f(x); }

// Pade[3/2] merged activation (r11 numerics): pre-scaled logits
__device__ __forceinline__ float act_h(float iv, float ov, float cv) {
    float ei = fexp2(iv);
    float eo = fexp2(ov);
    float u  = fexp2(cv);
    float p  = u - 1.0f;
    float q  = (1.0f + ei) * (u + 1.0f);     // cc = p/q = sig(i)*tanh(c~)
    float p2 = p * p, q2 = q * q;
    float t15 = 15.0f * q2;
    return (p * (t15 + p2)) * frcp((q * (6.0f * p2 + t15)) * (1.0f + eo));
}

__device__ __forceinline__ bf16x8 pack8(float4 v0, float4 v1) {
    bf16x8 a;
    a[0] = (short)f2bf(v0.x); a[1] = (short)f2bf(v0.y);
    a[2] = (short)f2bf(v0.z); a[3] = (short)f2bf(v0.w);
    a[4] = (short)f2bf(v1.x); a[5] = (short)f2bf(v1.y);
    a[6] = (short)f2bf(v1.z); a[7] = (short)f2bf(v1.w);
    return a;
}

// async global->LDS, 16B/lane; LDS dest = wave-uniform base + lane*16
__device__ __forceinline__ void gload_lds16(const void* gsrc, void* ldst) {
    __builtin_amdgcn_global_load_lds(
        (const __attribute__((address_space(1))) unsigned int*)gsrc,
        (__attribute__((address_space(3))) unsigned int*)ldst, 16, 0, 0);
}

// ---------------------------------------------------------------------------
// Prep (53 blocks x 256): ws layout identical to rounds 8-15.
//   [0,16384) emb frags; [16384,212992) gate frags; [212992,216064) biases.
// ---------------------------------------------------------------------------
__global__ void prep_frags(const float* __restrict__ embW,
                           const float* __restrict__ Wi,
                           const float* __restrict__ Wo,
                           const float* __restrict__ Wc,
                           const float* __restrict__ bWi, const float* __restrict__ bUi,
                           const float* __restrict__ bWo, const float* __restrict__ bUo,
                           const float* __restrict__ bWc, const float* __restrict__ bUc,
                           char* __restrict__ ws) {
    const int tid = threadIdx.x;
    const int fb  = blockIdx.x * 4 + (tid >> 6);
    const int l   = tid & 63;

    if (fb < 208) {
        int g  = l >> 4, c0 = l & 15;
        const float* src;
        int t, kk;
        size_t dst;
        float scale;
        if (fb < 16) {
            t = fb >> 1; kk = fb & 1;
            src = embW;                                   // [64][128]
            dst = (size_t)fb * 1024;
            scale = 1.0f;
        } else {
            int r = fb - 16;                              // (layer*8+t)*12+gate*4+kk
            int layer = r / 96;
            int r2 = r % 96;
            t = r2 / 12;
            int r3 = r2 % 12;
            int gate = r3 >> 2;
            kk = r3 & 3;
            const float* Ws[3] = {Wi, Wo, Wc};
            src = Ws[gate] + (size_t)layer * 128 * 128;   // [128][128]
            dst = 16384 + (size_t)r * 1024;
            scale = (gate == 2) ? TWO_L2E : NEG_L2E;
        }
        bf16x8 v;
#pragma unroll
        for (int e = 0; e < 8; ++e) {
            int k   = kk * 32 + g * 8 + e;
            int col = t * 16 + c0;
            v[e] = (short)f2bf(scale * src[(size_t)k * 128 + col]);
        }
        *reinterpret_cast<bf16x8*>(ws + dst + (size_t)l * 16) = v;
    } else if (blockIdx.x == 52) {
        float* bias = reinterpret_cast<float*>(ws + 212992);
#pragma unroll
        for (int j = 0; j < 3; ++j) {
            int v = j * 256 + tid;              // 0..767
            int layer = v / 384;
            int r = v % 384;
            int gate = r >> 7;
            int c = r & 127;
            int idx = layer * 128 + c;
            float x;
            if (gate == 0)      x = NEG_L2E * (bWi[idx] + bUi[idx]);
            else if (gate == 1) x = NEG_L2E * (bWo[idx] + bUo[idx]);
            else                x = TWO_L2E * (bWc[idx] + bUc[idx]);
            bias[v] = x;
        }
    }
}

// ---------------------------------------------------------------------------
// One step (L = S>>3, T = S&7).  Per step:
//   per-gate MFMA from sbuf -> barrier -> async-stage S+1 (global_load_lds)
//   -> activation (covers stage latency) -> barrier.
// ---------------------------------------------------------------------------
template<int S>
__device__ __forceinline__ void t_step(
        char* __restrict__ sbuf,
        const char* __restrict__ frags,
        bf16x8 (&A0)[4], bf16x8 (&A1)[4],
        unsigned short* __restrict__ slab,
        const float* __restrict__ biasf,
        float (* __restrict__ redbuf)[128],
        int w, int l, int g, int c0) {

    constexpr int L = S >> 3;
    constexpr int T = S & 7;
    const int c = T * 16 + c0;
    const float Bi = biasf[L * 384 + c];
    const float Bo = biasf[L * 384 + 128 + c];
    const float Bc = biasf[L * 384 + 256 + c];

    const bf16x8 (&A)[4] = (L == 0) ? A0 : A1;
    const char* sr = sbuf + (size_t)l * 16;

    f32x4 ai = {Bi, Bi, Bi, Bi};
    f32x4 ao = {Bo, Bo, Bo, Bo};
    f32x4 ac = {Bc, Bc, Bc, Bc};
    // per-gate loops: transient weight regs stay tiny (fits the 64-reg rung)
#pragma unroll
    for (int kk = 0; kk < 4; ++kk)
        ac = MFMA16(A[kk], *reinterpret_cast<const bf16x8*>(sr + (size_t)(8 + kk) * 1024), ac);
#pragma unroll
    for (int kk = 0; kk < 4; ++kk)
        ai = MFMA16(A[kk], *reinterpret_cast<const bf16x8*>(sr + (size_t)(0 + kk) * 1024), ai);
#pragma unroll
    for (int kk = 0; kk < 4; ++kk)
        ao = MFMA16(A[kk], *reinterpret_cast<const bf16x8*>(sr + (size_t)(4 + kk) * 1024), ao);

    __syncthreads();                 // all waves done reading sbuf for step S

    if (S < 15) {                    // async-stage step S+1 (no VGPRs)
        const char* gs = frags + 16384 + (size_t)(S + 1) * 12288;
#pragma unroll
        for (int i = 0; i < 3; ++i)
            gload_lds16(gs + (size_t)(i * 4096 + w * 1024) + (size_t)l * 16,
                        sbuf + i * 4096 + w * 1024);
    }

    // activation (registers only) — covers the staging latency
    float hsum = 0.0f;
#pragma unroll
    for (int r = 0; r < 4; ++r) {
        float h = act_h(ai[r], ao[r], ac[r]);
        if constexpr (L == 1) {
            hsum += h;
        } else {
            slab[(g * 4 + r) * 40 + (T & 1) * 16 + c0] = f2bf(h);
        }
    }
    if constexpr (L == 0) {
        if constexpr ((T & 1) == 1)   // pair complete -> A1 fragment (wave-private DS)
            A1[T >> 1] = *reinterpret_cast<const bf16x8*>(&slab[c0 * 40 + g * 8]);
    } else {
        hsum += __shfl_xor(hsum, 16);
        hsum += __shfl_xor(hsum, 32);
        if (g == 0) redbuf[w][c] = hsum;   // distinct cols per step: no clash
    }

    if (S < 15) __syncthreads();     // staged sbuf visible for step S+1
}

// ---------------------------------------------------------------------------
// Main kernel: 2048 blocks x 256 threads; 16 rows/wave; 8 blocks/CU.
// ---------------------------------------------------------------------------
__global__ __launch_bounds__(256, 8) void tree_enc(
        const float* __restrict__ X,       // [131072][64]
        const float* __restrict__ emb_b,   // [128]
        const char*  __restrict__ frags,   // ws
        float* __restrict__ out) {         // [256][128]

    __shared__ __align__(16) char sbuf[12288];                 // 12288 B
    __shared__ __align__(16) unsigned short slabs[4][16 * 40]; //  5120 B
    __shared__ float redbuf[4][128];                           //  2048 B

    const int tid = threadIdx.x;
    const int w   = tid >> 6;
    const int l   = tid & 63;
    const int g   = l >> 4;
    const int c0  = l & 15;
    const int rowbase = blockIdx.x * 64 + w * 16;
    const int batch   = blockIdx.x >> 3;        // 8 blocks per batch

    unsigned short* __restrict__ slab = slabs[w];
    const float* biasf = reinterpret_cast<const float*>(frags + 212992);

    // -------- async-stage step 0 weights (overlaps the whole embedding) ----
    {
        const char* gs = frags + 16384;
#pragma unroll
        for (int i = 0; i < 3; ++i)
            gload_lds16(gs + (size_t)(i * 4096 + w * 1024) + (size_t)l * 16,
                        sbuf + i * 4096 + w * 1024);
    }

    // -------- embedding: h0 for this wave's 16 rows -> slab -> A0 ----------
    bf16x8 A0[4], A1[4];
    {
        bf16x8 afr0, afr1;
        {
            const float* xr = X + (size_t)(rowbase + c0) * 64;
            float4 v0 = *reinterpret_cast<const float4*>(xr + g * 8);
            float4 v1 = *reinterpret_cast<const float4*>(xr + g * 8 + 4);
            float4 v2 = *reinterpret_cast<const float4*>(xr + 32 + g * 8);
            float4 v3 = *reinterpret_cast<const float4*>(xr + 32 + g * 8 + 4);
            afr0 = pack8(v0, v1);
            afr1 = pack8(v2, v3);
        }
#pragma unroll
        for (int t = 0; t < 8; ++t) {
            const char* eb = frags + (size_t)(t * 2) * 1024 + (size_t)l * 16;
            bf16x8 e0 = *reinterpret_cast<const bf16x8*>(eb);
            bf16x8 e1 = *reinterpret_cast<const bf16x8*>(eb + 1024);
            const float be = emb_b[t * 16 + c0];
            f32x4 acc = {be, be, be, be};
            acc = MFMA16(afr0, e0, acc);
            acc = MFMA16(afr1, e1, acc);
#pragma unroll
            for (int r = 0; r < 4; ++r)
                slab[(g * 4 + r) * 40 + (t & 1) * 16 + c0] = f2bf(acc[r]);
            if (t & 1)
                A0[t >> 1] = *reinterpret_cast<const bf16x8*>(&slab[c0 * 40 + g * 8]);
        }
    }
    __syncthreads();   // embedding done AND step-0 staging drained (vmcnt)

    // -------- 16 steps --------
    t_step< 0>(sbuf, frags, A0, A1, slab, biasf, redbuf, w, l, g, c0);
    t_step< 1>(sbuf, frags, A0, A1, slab, biasf, redbuf, w, l, g, c0);
    t_step< 2>(sbuf, frags, A0, A1, slab, biasf, redbuf, w, l, g, c0);
    t_step< 3>(sbuf, frags, A0, A1, slab, biasf, redbuf, w, l, g, c0);
    t_step< 4>(sbuf, frags, A0, A1, slab, biasf, redbuf, w, l, g, c0);
    t_step< 5>(sbuf, frags, A0, A1, slab, biasf, redbuf, w, l, g, c0);
    t_step< 6>(sbuf, frags, A0, A1, slab, biasf, redbuf, w, l, g, c0);
    t_step< 7>(sbuf, frags, A0, A1, slab, biasf, redbuf, w, l, g, c0);
    t_step< 8>(sbuf, frags, A0, A1, slab, biasf, redbuf, w, l, g, c0);
    t_step< 9>(sbuf, frags, A0, A1, slab, biasf, redbuf, w, l, g, c0);
    t_step<10>(sbuf, frags, A0, A1, slab, biasf, redbuf, w, l, g, c0);
    t_step<11>(sbuf, frags, A0, A1, slab, biasf, redbuf, w, l, g, c0);
    t_step<12>(sbuf, frags, A0, A1, slab, biasf, redbuf, w, l, g, c0);
    t_step<13>(sbuf, frags, A0, A1, slab, biasf, redbuf, w, l, g, c0);
    t_step<14>(sbuf, frags, A0, A1, slab, biasf, redbuf, w, l, g, c0);
    t_step<15>(sbuf, frags, A0, A1, slab, biasf, redbuf, w, l, g, c0);

    // -------- block reduce + one atomic per column --------
    __syncthreads();
    if (tid < 128) {
        float s = redbuf[0][tid] + redbuf[1][tid] + redbuf[2][tid] + redbuf[3][tid];
        atomicAdd(&out[batch * 128 + tid], s * (1.0f / 512.0f));
    }
}

// ---------------------------------------------------------------------------
extern "C" void kernel_launch(void* const* d_in, const int* in_sizes, int n_in,
                              void* d_out, int out_size, void* d_ws, size_t ws_size,
                              hipStream_t stream) {
    const float* X    = (const float*)d_in[0];
    const float* embW = (const float*)d_in[1];
    const float* embb = (const float*)d_in[2];
    const float* Wi   = (const float*)d_in[3];
    const float* Wo   = (const float*)d_in[4];
    const float* Wc   = (const float*)d_in[5];
    const float* bWi  = (const float*)d_in[6];
    const float* bUi  = (const float*)d_in[7];
    const float* bWo  = (const float*)d_in[8];
    const float* bUo  = (const float*)d_in[9];
    const float* bWc  = (const float*)d_in[10];
    const float* bUc  = (const float*)d_in[11];
    float* out = (float*)d_out;
    char*  ws  = (char*)d_ws;

    hipMemsetAsync(d_out, 0, (size_t)out_size * sizeof(float), stream);
    prep_frags<<<53, 256, 0, stream>>>(embW, Wi, Wo, Wc,
                                       bWi, bUi, bWo, bUo, bWc, bUc, ws);
    tree_enc<<<2048, 256, 0, stream>>>(X, embb, (const char*)ws, out);
}